// Round 13
// baseline (178.852 us; speedup 1.0000x reference)
//
#include <hip/hip_runtime.h>
#include <hip/hip_bf16.h>

#pragma clang fp contract(off)

typedef unsigned short u16;
typedef unsigned int u32;
typedef __attribute__((ext_vector_type(4))) float f32x4;
typedef __attribute__((ext_vector_type(8))) unsigned short u16x8;
typedef __attribute__((ext_vector_type(4))) unsigned short u16x4;
typedef __attribute__((ext_vector_type(4))) unsigned int u32x4;
typedef __attribute__((ext_vector_type(2))) unsigned int u32x2;

__device__ __forceinline__ float bf2f(u16 u) {
    union { unsigned int i; float f; } v; v.i = ((unsigned int)u) << 16; return v.f;
}
__device__ __forceinline__ u16 f2bf(float f) {
    __hip_bfloat16 h = __float2bfloat16(f);  // RNE
    return *(u16*)&h;
}
__device__ __forceinline__ float bflo(u32 w) {
    union { unsigned int i; float f; } v; v.i = w << 16; return v.f;
}
__device__ __forceinline__ float bfhi(u32 w) {
    union { unsigned int i; float f; } v; v.i = w & 0xffff0000u; return v.f;
}

__device__ __forceinline__ int cell_of(float x, float y, float z)
{
    int cx = (int)fminf(fmaxf((x + 1.0f) * 4.0f, 0.0f), 7.0f);
    int cy = (int)fminf(fmaxf((y + 1.0f) * 4.0f, 0.0f), 7.0f);
    int cz = (int)fminf(fmaxf((z + 1.0f) * 4.0f, 0.0f), 7.0f);
    return cx + (cy << 3) + (cz << 6);
}

// ---------------------------------------------------------------------------
// Fused prep + histogram kernel.
//   blocks [0,768):    plane record prep (which = b>>8)   stride 68
//   blocks [768,2816):  volume record prep                 stride 132
//   blocks [2816,3072): per-chunk 512-cell histogram (1024 points/chunk)
// Block 0 additionally computes the line-term constant into lcout[0].
// Record: [ECH x bf16 e | ECH x f32 g].
// ---------------------------------------------------------------------------
__global__ __launch_bounds__(256) void fused_prep_count(
    const float* __restrict__ pxy, const float* __restrict__ pxyg,
    const float* __restrict__ pyz, const float* __restrict__ pyzg,
    const float* __restrict__ pxz, const float* __restrict__ pxzg,
    const float* __restrict__ vol, const float* __restrict__ volg,
    char* __restrict__ tpxy, char* __restrict__ tpyz, char* __restrict__ tpxz,
    char* __restrict__ tv,
    const float* __restrict__ coords, u32* __restrict__ hist,
    float* __restrict__ lcout,
    const float* __restrict__ lx,  const float* __restrict__ ly,  const float* __restrict__ lz,
    const float* __restrict__ lxg, const float* __restrict__ lyg, const float* __restrict__ lzg,
    int P)
{
    __shared__ float smem[4352];          // 64*68 floats (>= 32*132)
    const int b = blockIdx.x;
    const int t = threadIdx.x;

    if (b < 768) {
        // ---- plane prep: CC=64, TP=64, ECH=32, RECB=192, stride=68 ----
        int which = b >> 8, blk = b & 255;
        const float* e = (which == 0) ? pxy  : (which == 1) ? pyz  : pxz;
        const float* g = (which == 0) ? pxyg : (which == 1) ? pyzg : pxzg;
        char* dst      = (which == 0) ? tpxy : (which == 1) ? tpyz : tpxz;
        const int tbase = blk * 64;
#pragma unroll
        for (int i = 0; i < 4; ++i) {
            int eidx = i * 256 + t;
            int c = eidx >> 4;
            int q = eidx & 15;
            const float* src = (c < 32) ? e : g;
            int cs = (c < 32) ? c : (c - 32);
            f32x4 v = *(const f32x4*)(src + (size_t)cs * 16384 + tbase + q * 4);
            *(f32x4*)&smem[c * 68 + q * 4] = v;
        }
        __syncthreads();
#pragma unroll
        for (int i = 0; i < 3; ++i) {
            int sid = i * 256 + t;
            int rec = sid / 12;
            int seg = sid % 12;
            char* outp = dst + (size_t)(tbase + rec) * 192 + seg * 16;
            if (seg < 4) {
                u16x8 pk;
#pragma unroll
                for (int k = 0; k < 8; ++k) pk[k] = f2bf(smem[(seg * 8 + k) * 68 + rec]);
                *(u16x8*)outp = pk;
            } else {
                f32x4 pk;
#pragma unroll
                for (int k = 0; k < 4; ++k) pk[k] = smem[(32 + (seg - 4) * 4 + k) * 68 + rec];
                *(f32x4*)outp = pk;
            }
        }
        if (b == 0 && t < 64) {
            float ev, gv, part = 0.0f;
            ev = lx[t * 128 + 63] * 0.5f + lx[t * 128 + 64] * 0.5f;
            gv = lxg[t * 128 + 63] * 0.5f + lxg[t * 128 + 64] * 0.5f;
            part += (gv >= 0.0f) ? ev : 0.0f;
            ev = ly[t * 128 + 63] * 0.5f + ly[t * 128 + 64] * 0.5f;
            gv = lyg[t * 128 + 63] * 0.5f + lyg[t * 128 + 64] * 0.5f;
            part += (gv >= 0.0f) ? ev : 0.0f;
            ev = lz[t * 128 + 63] * 0.5f + lz[t * 128 + 64] * 0.5f;
            gv = lzg[t * 128 + 63] * 0.5f + lzg[t * 128 + 64] * 0.5f;
            part += (gv >= 0.0f) ? ev : 0.0f;
#pragma unroll
            for (int off = 32; off > 0; off >>= 1) part += __shfl_down(part, off);
            if (t == 0) lcout[0] = part;
        }
    } else if (b < 2816) {
        // ---- volume prep: CC=32, TP=128, ECH=16, RECB=96, stride=132 ----
        int blk = b - 768;
        const int tbase = blk * 128;
#pragma unroll
        for (int i = 0; i < 4; ++i) {
            int eidx = i * 256 + t;
            int c = eidx >> 5;
            int q = eidx & 31;
            const float* src = (c < 16) ? vol : volg;
            int cs = (c < 16) ? c : (c - 16);
            f32x4 v = *(const f32x4*)(src + (size_t)cs * 262144 + tbase + q * 4);
            *(f32x4*)&smem[c * 132 + q * 4] = v;
        }
        __syncthreads();
#pragma unroll
        for (int i = 0; i < 3; ++i) {
            int sid = i * 256 + t;
            int rec = sid / 6;
            int seg = sid % 6;
            char* outp = tv + (size_t)(tbase + rec) * 96 + seg * 16;
            if (seg < 2) {
                u16x8 pk;
#pragma unroll
                for (int k = 0; k < 8; ++k) pk[k] = f2bf(smem[(seg * 8 + k) * 132 + rec]);
                *(u16x8*)outp = pk;
            } else {
                f32x4 pk;
#pragma unroll
                for (int k = 0; k < 4; ++k) pk[k] = smem[(16 + (seg - 2) * 4 + k) * 132 + rec];
                *(f32x4*)outp = pk;
            }
        }
    } else {
        // ---- histogram: 1024 points per chunk ----
        u32* h = (u32*)smem;
        int blk = b - 2816;
        h[t] = 0u; h[t + 256] = 0u;
        __syncthreads();
#pragma unroll
        for (int i = 0; i < 4; ++i) {
            int p = blk * 1024 + i * 256 + t;
            if (p < P) {
                float x = coords[3 * p + 0];
                float y = coords[3 * p + 1];
                float z = coords[3 * p + 2];
                atomicAdd(&h[cell_of(x, y, z)], 1u);
            }
        }
        __syncthreads();
        u32* hb = hist + (size_t)blk * 512;
        hb[t] = h[t];
        hb[t + 256] = h[t + 256];
    }
}

// ---------------------------------------------------------------------------
// Scatter (merged scan): 256 blocks x 1024 points. Each block reads the full
// hist coalescently, computes cell totals + its own block-prefix in registers,
// LDS-scans totals into global cell offsets, then ranks via LDS atomics and
// writes sorted {x,y,z,bits(p)}. Positions identical to two-kernel version.
// ---------------------------------------------------------------------------
__global__ __launch_bounds__(256) void scatter_sorted2(
    const float* __restrict__ coords, const u32* __restrict__ hist,
    f32x4* __restrict__ sorted, int P, int nb)
{
    __shared__ u32 lh[512];
    __shared__ u32 ts[512];
    __shared__ u32 st[512];
    int t = threadIdx.x;
    int b = blockIdx.x;

    u32 my0 = 0, my1 = 0, tot0 = 0, tot1 = 0;
#pragma unroll 8
    for (int bb = 0; bb < nb; ++bb) {
        u32 v0 = hist[(size_t)bb * 512 + t];
        u32 v1 = hist[(size_t)bb * 512 + t + 256];
        tot0 += v0; tot1 += v1;
        if (bb < b) { my0 += v0; my1 += v1; }
    }
    lh[t] = 0u; lh[t + 256] = 0u;
    ts[t] = tot0; ts[t + 256] = tot1;
    __syncthreads();
#pragma unroll
    for (int off = 1; off < 512; off <<= 1) {
        u32 x0 = (t >= off) ? ts[t - off] : 0u;
        u32 x1 = (t + 256 >= off) ? ts[t + 256 - off] : 0u;
        __syncthreads();
        ts[t] += x0; ts[t + 256] += x1;
        __syncthreads();
    }
    // exclusive global cell offset + this block's within-cell prefix
    st[t]       = ts[t]       - tot0 + my0;
    st[t + 256] = ts[t + 256] - tot1 + my1;
    __syncthreads();

#pragma unroll
    for (int i = 0; i < 4; ++i) {
        int p = b * 1024 + i * 256 + t;
        if (p < P) {
            float x = coords[3 * p + 0];
            float y = coords[3 * p + 1];
            float z = coords[3 * p + 2];
            int cell = cell_of(x, y, z);
            u32 rank = atomicAdd(&lh[cell], 1u);
            u32 pos = st[cell] + rank;
            f32x4 v = {x, y, z, __uint_as_float((u32)p)};
            sorted[pos] = v;
        }
    }
}

// ---------------------------------------------------------------------------
// Lane-split plane sampler: lane sub-index s (0..3) owns channels s*8..s*8+7.
// Record 192 B = [32 bf16 e | 32 f32 g]; g accumulated with exact mul+add in
// reference order (sign-critical); e via u32 pair-extraction (bit-identical)
// and fmaf (bf16-quantized, linear path).
// ---------------------------------------------------------------------------
__device__ __forceinline__ float plane_lane(
    const char* __restrict__ tp, float gx, float gy, int s)
{
    float ix = fminf(fmaxf((gx + 1.0f) * 0.5f * 127.0f, 0.0f), 127.0f);
    float iy = fminf(fmaxf((gy + 1.0f) * 0.5f * 127.0f, 0.0f), 127.0f);
    float x0f = floorf(ix), y0f = floorf(iy);
    float wx = ix - x0f, wy = iy - y0f;
    int x0 = (int)x0f, y0 = (int)y0f;
    int x1 = x0 + 1, y1 = y0 + 1;
    float vx1 = (x1 < 128) ? 1.0f : 0.0f;
    float vy1 = (y1 < 128) ? 1.0f : 0.0f;
    int x1c = min(x1, 127), y1c = min(y1, 127);
    float omwx = 1.0f - wx, omwy = 1.0f - wy;
    float ws4[4];
    ws4[0] = omwx * omwy;
    ws4[1] = (wx * omwy) * vx1;
    ws4[2] = (omwx * wy) * vy1;
    ws4[3] = ((wx * wy) * vx1) * vy1;
    unsigned o[4];
    o[0] = (unsigned)(y0  * 128 + x0 ) * 192u;
    o[1] = (unsigned)(y0  * 128 + x1c) * 192u;
    o[2] = (unsigned)(y1c * 128 + x0 ) * 192u;
    o[3] = (unsigned)(y1c * 128 + x1c) * 192u;

    const int eoff = s * 16;
    const int goff = 64 + s * 32;
    f32x4 ea0 = {0.0f, 0.0f, 0.0f, 0.0f}, ea1 = {0.0f, 0.0f, 0.0f, 0.0f};
    f32x4 ga0 = {0.0f, 0.0f, 0.0f, 0.0f}, ga1 = {0.0f, 0.0f, 0.0f, 0.0f};
#pragma unroll
    for (int t = 0; t < 4; ++t) {
        const char* bp = tp + o[t];
        float w = ws4[t];
        u32x4 ev = *(const u32x4*)(bp + eoff);
        f32x4 g0 = *(const f32x4*)(bp + goff);
        f32x4 g1 = *(const f32x4*)(bp + goff + 16);
#pragma unroll
        for (int j = 0; j < 4; ++j) {
            ga0[j] = ga0[j] + g0[j] * w;
            ga1[j] = ga1[j] + g1[j] * w;
        }
        ea0[0] = fmaf(bflo(ev[0]), w, ea0[0]);
        ea0[1] = fmaf(bfhi(ev[0]), w, ea0[1]);
        ea0[2] = fmaf(bflo(ev[1]), w, ea0[2]);
        ea0[3] = fmaf(bfhi(ev[1]), w, ea0[3]);
        ea1[0] = fmaf(bflo(ev[2]), w, ea1[0]);
        ea1[1] = fmaf(bfhi(ev[2]), w, ea1[1]);
        ea1[2] = fmaf(bflo(ev[3]), w, ea1[2]);
        ea1[3] = fmaf(bfhi(ev[3]), w, ea1[3]);
    }
    float acc = 0.0f;
#pragma unroll
    for (int j = 0; j < 4; ++j) {
        acc += (ga0[j] >= 0.0f) ? ea0[j] : 0.0f;
        acc += (ga1[j] >= 0.0f) ? ea1[j] : 0.0f;
    }
    return acc;
}

// ---------------------------------------------------------------------------
// Lane-split volume sampler: lane s owns channels s*4..s*4+3.
// Record 96 B = [16 bf16 e | 16 f32 g]; reference tt order (dz major).
// ---------------------------------------------------------------------------
__device__ __forceinline__ float vol_lane(
    const char* __restrict__ tv, float gx, float gy, float gz, int s)
{
    float ix = fminf(fmaxf((gx + 1.0f) * 0.5f * 63.0f, 0.0f), 63.0f);
    float iy = fminf(fmaxf((gy + 1.0f) * 0.5f * 63.0f, 0.0f), 63.0f);
    float iz = fminf(fmaxf((gz + 1.0f) * 0.5f * 63.0f, 0.0f), 63.0f);
    float x0f = floorf(ix), y0f = floorf(iy), z0f = floorf(iz);
    float wx = ix - x0f, wy = iy - y0f, wz = iz - z0f;
    int x0 = (int)x0f, y0 = (int)y0f, z0 = (int)z0f;
    int x1 = x0 + 1, y1 = y0 + 1, z1 = z0 + 1;
    float fx[2] = {1.0f - wx, wx}, fy[2] = {1.0f - wy, wy}, fz[2] = {1.0f - wz, wz};
    float vx[2] = {1.0f, (x1 < 64) ? 1.0f : 0.0f};
    float vy[2] = {1.0f, (y1 < 64) ? 1.0f : 0.0f};
    float vz[2] = {1.0f, (z1 < 64) ? 1.0f : 0.0f};
    int xi[2] = {x0, min(x1, 63)}, yi[2] = {y0, min(y1, 63)}, zi[2] = {z0, min(z1, 63)};

    unsigned off[8];
    float w[8];
#pragma unroll
    for (int dz = 0; dz < 2; ++dz)
#pragma unroll
        for (int dy = 0; dy < 2; ++dy)
#pragma unroll
            for (int dx = 0; dx < 2; ++dx) {
                int tt = (dz << 2) | (dy << 1) | dx;   // reference add order
                w[tt] = (((fx[dx] * fy[dy]) * fz[dz]) * vx[dx]) * (vy[dy] * vz[dz]);
                off[tt] = (unsigned)((zi[dz] * 64 + yi[dy]) * 64 + xi[dx]) * 96u;
            }
    const int eoff = s * 8;
    const int goff = 32 + s * 16;
    f32x4 ea = {0.0f, 0.0f, 0.0f, 0.0f}, ga = {0.0f, 0.0f, 0.0f, 0.0f};
#pragma unroll
    for (int tt = 0; tt < 8; ++tt) {
        const char* bp = tv + off[tt];
        float wt = w[tt];
        u32x2 ev = *(const u32x2*)(bp + eoff);
        f32x4 gv = *(const f32x4*)(bp + goff);
#pragma unroll
        for (int j = 0; j < 4; ++j)
            ga[j] = ga[j] + gv[j] * wt;
        ea[0] = fmaf(bflo(ev[0]), wt, ea[0]);
        ea[1] = fmaf(bfhi(ev[0]), wt, ea[1]);
        ea[2] = fmaf(bflo(ev[1]), wt, ea[2]);
        ea[3] = fmaf(bfhi(ev[1]), wt, ea[3]);
    }
    float acc = 0.0f;
#pragma unroll
    for (int j = 0; j < 4; ++j)
        acc += (ga[j] >= 0.0f) ? ea[j] : 0.0f;
    return acc;
}

// ---------------------------------------------------------------------------
// Main kernel: 4 lanes/point, 2 points per lane group, sorted float4 input.
// ---------------------------------------------------------------------------
__global__ __launch_bounds__(256) void ctri_main_S2(
    const f32x4* __restrict__ sorted, const float* __restrict__ lcbuf,
    const char* __restrict__ tpxy, const char* __restrict__ tpyz, const char* __restrict__ tpxz,
    const char* __restrict__ tv,
    float* __restrict__ out, int P, int nblk)
{
    float lc = lcbuf[0];
    int b = blockIdx.x;
    int cpx = nblk >> 3;                 // nblk multiple of 8
    int swz = (b & 7) * cpx + (b >> 3);  // XCD k <- contiguous sorted chunk
    int g = threadIdx.x >> 2;            // 0..63
    int s = threadIdx.x & 3;
    int i0 = swz * 128 + g * 2;
    if (i0 >= P) return;
    int i1 = min(i0 + 1, P - 1);
    f32x4 s0 = sorted[i0];
    f32x4 s1 = sorted[i1];
    int p0 = (int)__float_as_uint(s0[3]);
    int p1 = (int)__float_as_uint(s1[3]);
    float a0 = 0.0f, a1 = 0.0f;
    a0 += plane_lane(tpxy, s0[0], s0[1], s);    a1 += plane_lane(tpxy, s1[0], s1[1], s);
    a0 += plane_lane(tpyz, s0[1], s0[2], s);    a1 += plane_lane(tpyz, s1[1], s1[2], s);
    a0 += plane_lane(tpxz, s0[0], s0[2], s);    a1 += plane_lane(tpxz, s1[0], s1[2], s);
    a0 += vol_lane(tv, s0[0], s0[1], s0[2], s); a1 += vol_lane(tv, s1[0], s1[1], s1[2], s);
    a0 += __shfl_xor(a0, 1, 64);
    a0 += __shfl_xor(a0, 2, 64);
    a1 += __shfl_xor(a1, 1, 64);
    a1 += __shfl_xor(a1, 2, 64);
    if (s == 0) {
        out[p0] = lc + a0;
        if (i0 + 1 < P) out[p1] = lc + a1;
    }
}

// ---------------------------------------------------------------------------
// Direct-layout f32 fallback (used only if ws_size too small)
// ---------------------------------------------------------------------------
__device__ __forceinline__ float line_pair(const float* __restrict__ e,
                                           const float* __restrict__ g, int c)
{
    float ev = e[c * 128 + 63] * 0.5f + e[c * 128 + 64] * 0.5f;
    float gv = g[c * 128 + 63] * 0.5f + g[c * 128 + 64] * 0.5f;
    return (gv >= 0.0f) ? ev : 0.0f;
}

__device__ __forceinline__ float block_line_const(
    const float* lx, const float* ly, const float* lz,
    const float* lxg, const float* lyg, const float* lzg)
{
    __shared__ float lc_sh;
    int t = threadIdx.x;
    if (t < 64) {
        float part = line_pair(lx, lxg, t) + line_pair(ly, lyg, t) + line_pair(lz, lzg, t);
#pragma unroll
        for (int off = 32; off > 0; off >>= 1) part += __shfl_down(part, off);
        if (t == 0) lc_sh = part;
    }
    __syncthreads();
    return lc_sh;
}

__device__ __forceinline__ float sample_plane_pair_D(
    const float* __restrict__ e, const float* __restrict__ g, float gx, float gy)
{
    float ix = fminf(fmaxf((gx + 1.0f) * 0.5f * 127.0f, 0.0f), 127.0f);
    float iy = fminf(fmaxf((gy + 1.0f) * 0.5f * 127.0f, 0.0f), 127.0f);
    float x0f = floorf(ix), y0f = floorf(iy);
    float wx = ix - x0f, wy = iy - y0f;
    int x0 = (int)x0f, y0 = (int)y0f;
    int x1 = x0 + 1, y1 = y0 + 1;
    float vx1 = (x1 < 128) ? 1.0f : 0.0f;
    float vy1 = (y1 < 128) ? 1.0f : 0.0f;
    int x1c = min(x1, 127), y1c = min(y1, 127);
    float omwx = 1.0f - wx, omwy = 1.0f - wy;
    float w00 = omwx * omwy;
    float w10 = (wx * omwy) * vx1;
    float w01 = (omwx * wy) * vy1;
    float w11 = ((wx * wy) * vx1) * vy1;
    int o00 = y0 * 128 + x0, o10 = y0 * 128 + x1c;
    int o01 = y1c * 128 + x0, o11 = y1c * 128 + x1c;
    float acc = 0.0f;
#pragma unroll 4
    for (int c = 0; c < 32; ++c) {
        const float* ec = e + (size_t)c * 16384;
        const float* gc = g + (size_t)c * 16384;
        float ei = ((ec[o00] * w00 + ec[o10] * w10) + ec[o01] * w01) + ec[o11] * w11;
        float gi = ((gc[o00] * w00 + gc[o10] * w10) + gc[o01] * w01) + gc[o11] * w11;
        acc += (gi >= 0.0f) ? ei : 0.0f;
    }
    return acc;
}

__device__ __forceinline__ float sample_volume_D(
    const float* __restrict__ e, const float* __restrict__ g,
    float gx, float gy, float gz)
{
    float ix = fminf(fmaxf((gx + 1.0f) * 0.5f * 63.0f, 0.0f), 63.0f);
    float iy = fminf(fmaxf((gy + 1.0f) * 0.5f * 63.0f, 0.0f), 63.0f);
    float iz = fminf(fmaxf((gz + 1.0f) * 0.5f * 63.0f, 0.0f), 63.0f);
    float x0f = floorf(ix), y0f = floorf(iy), z0f = floorf(iz);
    float wx = ix - x0f, wy = iy - y0f, wz = iz - z0f;
    int x0 = (int)x0f, y0 = (int)y0f, z0 = (int)z0f;
    int x1 = x0 + 1, y1 = y0 + 1, z1 = z0 + 1;
    float fx[2] = {1.0f - wx, wx}, fy[2] = {1.0f - wy, wy}, fz[2] = {1.0f - wz, wz};
    float vx[2] = {1.0f, (x1 < 64) ? 1.0f : 0.0f};
    float vy[2] = {1.0f, (y1 < 64) ? 1.0f : 0.0f};
    float vz[2] = {1.0f, (z1 < 64) ? 1.0f : 0.0f};
    int xi[2] = {x0, min(x1, 63)}, yi[2] = {y0, min(y1, 63)}, zi[2] = {z0, min(z1, 63)};
    int o[8]; float w[8];
#pragma unroll
    for (int dz = 0; dz < 2; ++dz)
#pragma unroll
        for (int dy = 0; dy < 2; ++dy)
#pragma unroll
            for (int dx = 0; dx < 2; ++dx) {
                int tt = (dz << 2) | (dy << 1) | dx;
                w[tt] = (((fx[dx] * fy[dy]) * fz[dz]) * vx[dx]) * (vy[dy] * vz[dz]);
                o[tt] = (zi[dz] * 64 + yi[dy]) * 64 + xi[dx];
            }
    float acc = 0.0f;
#pragma unroll 2
    for (int c = 0; c < 16; ++c) {
        const float* ec = e + (size_t)c * 262144;
        const float* gc = g + (size_t)c * 262144;
        float ei = 0.0f, gi = 0.0f;
#pragma unroll
        for (int tt = 0; tt < 8; ++tt) {
            ei = ei + ec[o[tt]] * w[tt];
            gi = gi + gc[o[tt]] * w[tt];
        }
        acc += (gi >= 0.0f) ? ei : 0.0f;
    }
    return acc;
}

__global__ __launch_bounds__(256) void ctri_main_D(
    const float* __restrict__ coords,
    const float* __restrict__ lx,  const float* __restrict__ ly,  const float* __restrict__ lz,
    const float* __restrict__ lxg, const float* __restrict__ lyg, const float* __restrict__ lzg,
    const float* __restrict__ pxy, const float* __restrict__ pyz, const float* __restrict__ pxz,
    const float* __restrict__ pxyg, const float* __restrict__ pyzg, const float* __restrict__ pxzg,
    const float* __restrict__ vol, const float* __restrict__ volg,
    float* __restrict__ out, int P)
{
    float lc = block_line_const(lx, ly, lz, lxg, lyg, lzg);
    int p = blockIdx.x * blockDim.x + threadIdx.x;
    if (p >= P) return;
    float x = coords[3 * p + 0];
    float y = coords[3 * p + 1];
    float z = coords[3 * p + 2];
    float acc = lc;
    acc += sample_plane_pair_D(pxy, pxyg, x, y);
    acc += sample_plane_pair_D(pyz, pyzg, y, z);
    acc += sample_plane_pair_D(pxz, pxzg, x, z);
    acc += sample_volume_D(vol, volg, x, y, z);
    out[p] = acc;
}

// ---------------------------------------------------------------------------
extern "C" void kernel_launch(void* const* d_in, const int* in_sizes, int n_in,
                              void* d_out, int out_size, void* d_ws, size_t ws_size,
                              hipStream_t stream)
{
    (void)n_in; (void)out_size;
    const float* coords = (const float*)d_in[0];
    const float* pxy  = (const float*)d_in[1];
    const float* pyz  = (const float*)d_in[2];
    const float* pxz  = (const float*)d_in[3];
    const float* pxyg = (const float*)d_in[4];
    const float* pyzg = (const float*)d_in[5];
    const float* pxzg = (const float*)d_in[6];
    const float* lx   = (const float*)d_in[7];
    const float* ly   = (const float*)d_in[8];
    const float* lz   = (const float*)d_in[9];
    const float* lxg  = (const float*)d_in[10];
    const float* lyg  = (const float*)d_in[11];
    const float* lzg  = (const float*)d_in[12];
    const float* vol  = (const float*)d_in[13];
    const float* volg = (const float*)d_in[14];
    float* out = (float*)d_out;

    const int P = in_sizes[0] / 3;                        // 262144
    const int chunks = (P + 1023) / 1024;                 // 256
    const size_t planeRec = (size_t)16384 * 192;          // 3 MB each
    const size_t volRec   = (size_t)262144 * 96;          // 24 MB
    const size_t tabBytes = 3 * planeRec + volRec;        // ~34.6 MB
    const size_t sortBytes = (size_t)P * 16;              // 4 MB
    const size_t histBytes = (size_t)chunks * 512 * 4;    // 512 KB
    const size_t need_bytes = tabBytes + sortBytes + histBytes + 64;

    if (ws_size >= need_bytes) {
        char* tpxy = (char*)d_ws;
        char* tpyz = tpxy + planeRec;
        char* tpxz = tpyz + planeRec;
        char* tv   = tpxz + planeRec;
        f32x4* sorted = (f32x4*)(tv + volRec);
        u32* hist    = (u32*)(sorted + P);
        float* lcbuf = (float*)(hist + (size_t)chunks * 512);

        fused_prep_count<<<2816 + chunks, 256, 0, stream>>>(
            pxy, pxyg, pyz, pyzg, pxz, pxzg, vol, volg,
            tpxy, tpyz, tpxz, tv, coords, hist, lcbuf,
            lx, ly, lz, lxg, lyg, lzg, P);
        scatter_sorted2<<<chunks, 256, 0, stream>>>(coords, hist, sorted, P, chunks);

        const int mblocks = (P * 2 + 255) / 256;          // 2048, multiple of 8
        ctri_main_S2<<<mblocks, 256, 0, stream>>>(sorted, lcbuf,
                                                  tpxy, tpyz, tpxz, tv, out, P, mblocks);
    } else {
        const int pblocks = (P + 255) / 256;
        ctri_main_D<<<pblocks, 256, 0, stream>>>(coords, lx, ly, lz, lxg, lyg, lzg,
                                                 pxy, pyz, pxz, pxyg, pyzg, pxzg,
                                                 vol, volg, out, P);
    }
}